// Round 2
// baseline (228.913 us; speedup 1.0000x reference)
//
#include <hip/hip_runtime.h>
#include <math.h>

#define NCH  256
#define CROP 7
#define NPIX 49

typedef float vf4 __attribute__((ext_vector_type(4)));

__device__ __forceinline__ float lerpf(float a, float b, float t) {
    return a + (b - a) * t;
}

// One block = half an ROI (28 / 21 pixels), 256 threads = 4 pixels x 64
// channel-quads per iteration. grid = (2, N). Same-ROI corner rows are
// reused through L1/L2 within the block (vs round-robin XCD spread).
__global__ __launch_bounds__(256) void roialign_fpn_kernel(
    const float* __restrict__ p2, const float* __restrict__ p3,
    const float* __restrict__ p4, const float* __restrict__ p5,
    const float* __restrict__ rois, const int* __restrict__ bidx,
    float* __restrict__ out, float* __restrict__ out_tail)
{
    const int tid  = threadIdx.x;
    const int cv   = tid & 63;            // channel quad: c = 4*cv
    const int pl   = tid >> 6;            // wave id 0..3 (pixel lane)
    const int half = blockIdx.x;          // 0: pix 0..27, 1: pix 28..48
    const int n    = blockIdx.y;

    // ROI box [x1,y1,x2,y2] in image coords
    const float rx1 = rois[4*n+0];
    const float ry1 = rois[4*n+1];
    const float rx2 = rois[4*n+2];
    const float ry2 = rois[4*n+3];
    const float w = rx2 - rx1;
    const float h = ry2 - ry1;

    // level = clip(round(log2(sqrt(h*w)/224) + 4), 2, 5); rintf = half-to-even
    const float lvlf = logf(sqrtf(h * w) / 224.0f) / logf(2.0f) + 4.0f;
    int lvl = (int)rintf(lvlf);
    lvl = lvl < 2 ? 2 : (lvl > 5 ? 5 : lvl);
    const int i = lvl - 2;                // 0..3 -> p2..p5, stride 4<<i

    const int H = 256 >> i;               // H == W (square maps)
    const float* fm = (i == 0) ? p2 : (i == 1) ? p3 : (i == 2) ? p4 : p5;
    // ref: (roi/stride)/H — both pow2 -> exact as one reciprocal multiply
    const float inv = 1.0f / (float)((4 << i) * H);
    const float Hm1 = (float)(H - 1);

    const int b = bidx[n];
    if (half == 0 && tid == 0) out_tail[n] = (float)b;  // 2nd tuple output

    const float ny1 = ry1 * inv, ny2 = ry2 * inv;
    const float nx1 = rx1 * inv, nx2 = rx2 * inv;
    const size_t bbase = (size_t)b * H * H;

    const int c = cv * 4;
    float* outp = out + (size_t)n * (NPIX * NCH) + c;

    const int pix0  = half * 28;
    const int iters = half ? 6 : 7;       // 28 pixels / 24 slots (3 idle)

    for (int it = 0; it < iters; ++it) {
        const int pix = pix0 + it * 4 + pl;
        if (pix >= NPIX) continue;        // wave-uniform (pl uniform per wave)

        const int jy = pix / CROP;
        const int jx = pix - jy * CROP;
        // g = j/6.0 as float division to match np bit-for-bit
        const float gy = (float)jy / 6.0f;
        const float gx = (float)jx / 6.0f;
        const float in_y = (ny1 + (ny2 - ny1) * gy) * Hm1;
        const float in_x = (nx1 + (nx2 - nx1) * gx) * Hm1;

        const bool valid = (in_y >= 0.0f) && (in_y <= Hm1) &&
                           (in_x >= 0.0f) && (in_x <= Hm1);

        const float y0f = floorf(in_y);
        const float x0f = floorf(in_x);
        const float ly = in_y - y0f;
        const float lx = in_x - x0f;
        const int y0 = (int)fminf(fmaxf(y0f,         0.0f), Hm1);
        const int y1 = (int)fminf(fmaxf(ceilf(in_y), 0.0f), Hm1);
        const int x0 = (int)fminf(fmaxf(x0f,         0.0f), Hm1);
        const int x1 = (int)fminf(fmaxf(ceilf(in_x), 0.0f), Hm1);

        const size_t row0 = bbase + (size_t)y0 * H;
        const size_t row1 = bbase + (size_t)y1 * H;

        const vf4 tl = *(const vf4*)(fm + (row0 + x0) * NCH + c);
        const vf4 tr = *(const vf4*)(fm + (row0 + x1) * NCH + c);
        const vf4 bl = *(const vf4*)(fm + (row1 + x0) * NCH + c);
        const vf4 br = *(const vf4*)(fm + (row1 + x1) * NCH + c);

        vf4 r;
        r.x = lerpf(lerpf(tl.x, tr.x, lx), lerpf(bl.x, br.x, lx), ly);
        r.y = lerpf(lerpf(tl.y, tr.y, lx), lerpf(bl.y, br.y, lx), ly);
        r.z = lerpf(lerpf(tl.z, tr.z, lx), lerpf(bl.z, br.z, lx), ly);
        r.w = lerpf(lerpf(tl.w, tr.w, lx), lerpf(bl.w, br.w, lx), ly);
        if (!valid) { r.x = 0.0f; r.y = 0.0f; r.z = 0.0f; r.w = 0.0f; }

        // write-once 50 MB output: nt store keeps L2 for feature-map reads
        __builtin_nontemporal_store(r, (vf4*)(outp + (size_t)pix * NCH));
    }
}

extern "C" void kernel_launch(void* const* d_in, const int* in_sizes, int n_in,
                              void* d_out, int out_size, void* d_ws, size_t ws_size,
                              hipStream_t stream) {
    const float* p2   = (const float*)d_in[0];
    const float* p3   = (const float*)d_in[1];
    const float* p4   = (const float*)d_in[2];
    const float* p5   = (const float*)d_in[3];
    const float* rois = (const float*)d_in[4];
    const int*   bidx = (const int*)d_in[5];
    float* out = (float*)d_out;

    const int N = in_sizes[5];            // number of ROIs
    float* tail = out + (size_t)N * (NPIX * NCH);

    dim3 grid(2, N);                      // 2000 blocks
    roialign_fpn_kernel<<<grid, 256, 0, stream>>>(p2, p3, p4, p5, rois, bidx,
                                                  out, tail);
}

// Round 3
// 228.076 us; speedup vs baseline: 1.0037x; 1.0037x over previous
//
#include <hip/hip_runtime.h>
#include <math.h>

#define NCH  256
#define CROP 7
#define NPIX 49

typedef float vf4 __attribute__((ext_vector_type(4)));

__device__ __forceinline__ float lerpf(float a, float b, float t) {
    return a + (b - a) * t;
}

// One block = one ROI. 256 threads = 4 pixel-waves x 64 channel-quads.
// 13 iterations cover 49 pixels (3 idle slots, predicated store only —
// loads stay unconditional so the compiler can pipeline them).
__global__ __launch_bounds__(256) void roialign_fpn_kernel(
    const float* __restrict__ p2, const float* __restrict__ p3,
    const float* __restrict__ p4, const float* __restrict__ p5,
    const float* __restrict__ rois, const int* __restrict__ bidx,
    float* __restrict__ out, float* __restrict__ out_tail)
{
    const int tid = threadIdx.x;
    const int cv  = tid & 63;             // channel quad: c = 4*cv
    const int pl  = tid >> 6;             // wave id 0..3 (pixel slot)
    const int n   = blockIdx.x;

    // ROI box [x1,y1,x2,y2] in image coords (vector load)
    const vf4 rb = *(const vf4*)(rois + 4 * n);
    const float rx1 = rb.x, ry1 = rb.y, rx2 = rb.z, ry2 = rb.w;
    const float w = rx2 - rx1;
    const float h = ry2 - ry1;

    // level = clip(round(log2(sqrt(h*w)/224) + 4), 2, 5); rintf = half-to-even
    const float lvlf = logf(sqrtf(h * w) / 224.0f) / logf(2.0f) + 4.0f;
    int lvl = (int)rintf(lvlf);
    lvl = lvl < 2 ? 2 : (lvl > 5 ? 5 : lvl);
    const int i = lvl - 2;                // 0..3 -> p2..p5, stride 4<<i

    const int H = 256 >> i;               // H == W (square maps)
    const float* fm = (i == 0) ? p2 : (i == 1) ? p3 : (i == 2) ? p4 : p5;
    // ref: (roi/stride)/H — both pow2 -> exact as one reciprocal multiply
    const float inv = 1.0f / (float)((4 << i) * H);
    const float Hm1 = (float)(H - 1);

    const int b = bidx[n];
    if (tid == 0) out_tail[n] = (float)b;  // 2nd tuple output

    const float ny1 = ry1 * inv, ny2 = ry2 * inv;
    const float nx1 = rx1 * inv, nx2 = rx2 * inv;
    const size_t bbase = (size_t)b * H * H;

    const int c = cv * 4;
    float* outp = out + (size_t)n * (NPIX * NCH) + c;

#pragma unroll 4
    for (int it = 0; it < 13; ++it) {
        const int slot = it * 4 + pl;      // 0..51
        const int pix  = slot < NPIX ? slot : NPIX - 1;   // clamp, store predicated

        const int jy = pix / CROP;
        const int jx = pix - jy * CROP;
        // g = j/6.0 as float division to match np bit-for-bit
        const float gy = (float)jy / 6.0f;
        const float gx = (float)jx / 6.0f;
        const float in_y = (ny1 + (ny2 - ny1) * gy) * Hm1;
        const float in_x = (nx1 + (nx2 - nx1) * gx) * Hm1;

        const bool valid = (in_y >= 0.0f) && (in_y <= Hm1) &&
                           (in_x >= 0.0f) && (in_x <= Hm1);

        const float y0f = floorf(in_y);
        const float x0f = floorf(in_x);
        const float ly = in_y - y0f;
        const float lx = in_x - x0f;
        const int y0 = (int)fminf(fmaxf(y0f,         0.0f), Hm1);
        const int y1 = (int)fminf(fmaxf(ceilf(in_y), 0.0f), Hm1);
        const int x0 = (int)fminf(fmaxf(x0f,         0.0f), Hm1);
        const int x1 = (int)fminf(fmaxf(ceilf(in_x), 0.0f), Hm1);

        const size_t row0 = bbase + (size_t)y0 * H;
        const size_t row1 = bbase + (size_t)y1 * H;

        const vf4 tl = *(const vf4*)(fm + (row0 + x0) * NCH + c);
        const vf4 tr = *(const vf4*)(fm + (row0 + x1) * NCH + c);
        const vf4 bl = *(const vf4*)(fm + (row1 + x0) * NCH + c);
        const vf4 br = *(const vf4*)(fm + (row1 + x1) * NCH + c);

        vf4 r;
        r.x = lerpf(lerpf(tl.x, tr.x, lx), lerpf(bl.x, br.x, lx), ly);
        r.y = lerpf(lerpf(tl.y, tr.y, lx), lerpf(bl.y, br.y, lx), ly);
        r.z = lerpf(lerpf(tl.z, tr.z, lx), lerpf(bl.z, br.z, lx), ly);
        r.w = lerpf(lerpf(tl.w, tr.w, lx), lerpf(bl.w, br.w, lx), ly);
        if (!valid) { r.x = 0.0f; r.y = 0.0f; r.z = 0.0f; r.w = 0.0f; }

        if (slot < NPIX) {
            // write-once 50 MB output: nt store keeps L2 for fm reads
            __builtin_nontemporal_store(r, (vf4*)(outp + (size_t)pix * NCH));
        }
    }
}

extern "C" void kernel_launch(void* const* d_in, const int* in_sizes, int n_in,
                              void* d_out, int out_size, void* d_ws, size_t ws_size,
                              hipStream_t stream) {
    const float* p2   = (const float*)d_in[0];
    const float* p3   = (const float*)d_in[1];
    const float* p4   = (const float*)d_in[2];
    const float* p5   = (const float*)d_in[3];
    const float* rois = (const float*)d_in[4];
    const int*   bidx = (const int*)d_in[5];
    float* out = (float*)d_out;

    const int N = in_sizes[5];            // number of ROIs
    float* tail = out + (size_t)N * (NPIX * NCH);

    roialign_fpn_kernel<<<N, 256, 0, stream>>>(p2, p3, p4, p5, rois, bidx,
                                               out, tail);
}